// Round 12
// baseline (295.363 us; speedup 1.0000x reference)
//
#include <hip/hip_runtime.h>

#define EPS 1e-5f
#define APITCH 264   // bf16 tile row pitch (shorts); 528B rows, 16B-aligned

typedef __attribute__((ext_vector_type(8))) short bf16x8;
typedef __attribute__((ext_vector_type(4))) float f32x4;

// RTNE (one-time weight conversion)
__device__ __forceinline__ unsigned short f2b_rtne(float f) {
  unsigned u = __builtin_bit_cast(unsigned, f);
  u += 0x7fffu + ((u >> 16) & 1u);
  return (unsigned short)(u >> 16);
}
// HW packed f32->2xbf16 (RTNE)
__device__ __forceinline__ unsigned cvt_pk(float lo, float hi) {
  unsigned r;
  asm("v_cvt_pk_bf16_f32 %0, %1, %2" : "=v"(r) : "v"(lo), "v"(hi));
  return r;
}
__device__ __forceinline__ float bhalf(unsigned pk, int hi) {
  unsigned u = hi ? (pk & 0xffff0000u) : (pk << 16);
  return __builtin_bit_cast(float, u);
}
__device__ __forceinline__ int div9(int r) {
  return (int)(__umulhi((unsigned)r, 954437177u) >> 1);
}
// select gio word for (rh, half) — constant-folded under full unroll
__device__ __forceinline__ unsigned gsel(const uint4& g, int rh, int half) {
  return rh ? (half ? g.w : g.z) : (half ? g.y : g.x);
}

// Convert all 5 weight matrices into MFMA-fragment-linear bf16 (contiguous dst).
// ig/ug/fc k-index pre-permuted for the pi-packed LDS tiles (see R11).
__global__ void k_cvt_all(const float* __restrict__ dynW, const float* __restrict__ inpW,
                          const float* __restrict__ igW, const float* __restrict__ ugW,
                          const float* __restrict__ fcW, unsigned short* __restrict__ dst) {
  int i = blockIdx.x * blockDim.x + threadIdx.x;   // [0, 458752)
  const float* src; int off; int perm;
  if (i < 131072)      { src = dynW; off = i;          perm = 0; }
  else if (i < 262144) { src = inpW; off = i - 131072; perm = 0; }
  else if (i < 327680) { src = igW;  off = i - 262144; perm = 1; }
  else if (i < 393216) { src = ugW;  off = i - 327680; perm = 1; }
  else                 { src = fcW;  off = i - 393216; perm = 1; }
  int j = off & 7, lane = (off >> 3) & 63, kk = (off >> 9) & 7, ct = off >> 12;
  int row = ct * 16 + (lane & 15);
  int p = kk * 32 + (lane >> 4) * 8 + j;           // k position in fragment order
  int col = perm ? ((p & ~63) + (p & 3) * 16 + ((p >> 2) & 15)) : p;
  dst[i] = f2b_rtne(src[row * 256 + col]);
}

// ================= 32-row main kernel (R9 bursts, gio in dead-LDS) =================
// gio (16 persistent VGPRs in R9-R11) now lives in the aT tile's dead window
// (PH1-epi .. PH3-epi), private per-thread slots gioL[q*256+t] -> target
// ~96 arch + 32 AGPR = 128 total (4-waves/SIMD tier). Burst structure (b[8]
// -> 16 MFMA, a re-read per q) unchanged — R10 showed splitting it costs 33%.

__device__ __forceinline__ void gemmQ(const short* src,
                                      const unsigned short* __restrict__ W,
                                      f32x4 (&acc)[4][2],
                                      int wv, int lane, int lr, int lh) {
#pragma unroll
  for (int q = 0; q < 4; q++) {
    const unsigned short* Wp = W + ((wv * 4 + q) << 12) + lane * 8;
    bf16x8 b[8];
#pragma unroll
    for (int kk = 0; kk < 8; kk++) b[kk] = *(const bf16x8*)&Wp[kk * 512];
    int zoff = 0;
    asm volatile("" : "+v"(zoff));          // opaque 0: forces a re-read each q
    const short* ap = src + zoff;
    bf16x8 a[8];
#pragma unroll
    for (int kk = 0; kk < 8; kk++)
      a[kk] = *(const bf16x8*)&ap[lr * APITCH + kk * 32 + lh * 8];
    acc[q][0] = (f32x4){0.f, 0.f, 0.f, 0.f};
#pragma unroll
    for (int kk = 0; kk < 8; kk++)
      acc[q][0] = __builtin_amdgcn_mfma_f32_16x16x32_bf16(a[kk], b[kk], acc[q][0], 0, 0, 0);
#pragma unroll
    for (int kk = 0; kk < 8; kk++)
      a[kk] = *(const bf16x8*)&ap[(16 + lr) * APITCH + kk * 32 + lh * 8];
    acc[q][1] = (f32x4){0.f, 0.f, 0.f, 0.f};
#pragma unroll
    for (int kk = 0; kk < 8; kk++)
      acc[q][1] = __builtin_amdgcn_mfma_f32_16x16x32_bf16(a[kk], b[kk], acc[q][1], 0, 0, 0);
  }
}

__device__ __forceinline__ void statsW(const f32x4 (&acc)[4][2], const float (&b4)[4],
                                       float* sP, float* qP, int wv, int lr, int lh) {
#pragma unroll
  for (int rh = 0; rh < 2; rh++)
#pragma unroll
    for (int i = 0; i < 4; i++) {
      float s = 0.f, qq = 0.f;
#pragma unroll
      for (int q = 0; q < 4; q++) { float v = acc[q][rh][i] + b4[q]; s += v; qq += v * v; }
#pragma unroll
      for (int m = 1; m < 16; m <<= 1) { s += __shfl_xor(s, m); qq += __shfl_xor(qq, m); }
      if (lr == 0) {
        int r = rh * 16 + lh * 4 + i;
        sP[wv * 32 + r] = s; qP[wv * 32 + r] = qq;
      }
    }
}
__device__ __forceinline__ void statsR(const float* sP, const float* qP,
                                       float (&mu)[2][4], float (&rs)[2][4], int lh) {
#pragma unroll
  for (int rh = 0; rh < 2; rh++)
#pragma unroll
    for (int i = 0; i < 4; i++) {
      int r = rh * 16 + lh * 4 + i;
      float S = sP[r] + sP[32 + r] + sP[64 + r] + sP[96 + r];
      float Q = qP[r] + qP[32 + r] + qP[64 + r] + qP[96 + r];
      float m = S * (1.f / 256.f);
      mu[rh][i] = m;
      rs[rh][i] = rsqrtf(Q * (1.f / 256.f) - m * m + EPS);
    }
}

// NOTE: no min-waves arg — a second __launch_bounds__ argument caps arch-VGPR at
// 256/minwaves on MFMA kernels (observed R2-R4) and forces scratch.
__global__ __launch_bounds__(256) void k_main(
    const float* __restrict__ inf,
    const unsigned short* __restrict__ inpWf, const float* __restrict__ inpb,
    const unsigned short* __restrict__ igWf, const float* __restrict__ igb,
    const unsigned short* __restrict__ ugWf, const float* __restrict__ ugb,
    const unsigned short* __restrict__ fcWf, const float* __restrict__ fcb,
    const float* __restrict__ nig, const float* __restrict__ nib,
    const float* __restrict__ iig, const float* __restrict__ iib,
    const float* __restrict__ iog, const float* __restrict__ iob,
    const float* __restrict__ fng, const float* __restrict__ fnb,
    const float* __restrict__ param_in, const float* __restrict__ param_out_ln,
    float* __restrict__ out) {
  __shared__ short aT[32 * APITCH];
  __shared__ short gT[32 * APITCH];
  __shared__ float sP[2][128], qP[2][128];
  uint4* gioL = (uint4*)aT;   // 4*256*16B = 16384B <= 16896B; live PH1-epi..PH3-epi
                              // (aT's gemm reads end at PH1; features rewrite at PH3-epi)

  const int t = threadIdx.x;
  const int wv = t >> 6, lane = t & 63, lr = lane & 15, lh = lane >> 4;
  const int cb = wv * 64;
  const int r0 = blockIdx.x * 32;

  // stage 32x256 f32 -> bf16 LDS (coalesced float4 in, packed b64 out)
#pragma unroll
  for (int j = 0; j < 8; j++) {
    const int idx4 = j * 256 + t;
    const int row = idx4 >> 6;
    const int c4 = (idx4 & 63) << 2;
    const float4 v = *(const float4*)&inf[(size_t)(r0 + row) * 256 + c4];
    uint2 pk;
    pk.x = cvt_pk(v.x, v.y);
    pk.y = cvt_pk(v.z, v.w);
    *(uint2*)&aT[row * APITCH + c4] = pk;
  }
  __syncthreads();

  f32x4 acc[4][2];
  float b4[4], mu[2][4], rs[2][4], gA[4], bB4[4];

  // ---- PH0: input_in -> gate_feats -> gT (pi-layout, packed 8B writes) ----
  gemmQ(aT, inpWf, acc, wv, lane, lr, lh);
#pragma unroll
  for (int q = 0; q < 4; q++) b4[q] = inpb[cb + q * 16 + lr];
#pragma unroll
  for (int rh = 0; rh < 2; rh++)
#pragma unroll
    for (int i = 0; i < 4; i++) {
      const int rr = rh * 16 + lh * 4 + i;
      const float* pin = param_in + (size_t)div9(r0 + rr) * 256;
      float g[4];
#pragma unroll
      for (int q = 0; q < 4; q++)
        g[q] = (acc[q][rh][i] + b4[q]) * pin[cb + q * 16 + lr];
      uint2 pk;
      pk.x = cvt_pk(g[0], g[1]);
      pk.y = cvt_pk(g[2], g[3]);
      *(uint2*)&gT[rr * APITCH + cb + lr * 4] = pk;   // pi position
    }

  // ---- PH1: input_out, LN -> gioL (aT reads done; region dead) ----
  gemmQ(aT, inpWf + (16 << 12), acc, wv, lane, lr, lh);
#pragma unroll
  for (int q = 0; q < 4; q++) b4[q] = inpb[256 + cb + q * 16 + lr];
  statsW(acc, b4, sP[1], qP[1], wv, lr, lh);
  __syncthreads();   // S2: publishes gT + stats; all aT gemm-reads complete
  statsR(sP[1], qP[1], mu, rs, lh);
#pragma unroll
  for (int q = 0; q < 4; q++) { gA[q] = iog[cb + q * 16 + lr]; bB4[q] = iob[cb + q * 16 + lr]; }
#pragma unroll
  for (int q = 0; q < 4; q++) {
    uint4 gv;
    {
      float v0 = (acc[q][0][0] + b4[q] - mu[0][0]) * rs[0][0] * gA[q] + bB4[q];
      float v1 = (acc[q][0][1] + b4[q] - mu[0][1]) * rs[0][1] * gA[q] + bB4[q];
      float v2 = (acc[q][0][2] + b4[q] - mu[0][2]) * rs[0][2] * gA[q] + bB4[q];
      float v3 = (acc[q][0][3] + b4[q] - mu[0][3]) * rs[0][3] * gA[q] + bB4[q];
      gv.x = cvt_pk(v0, v1);
      gv.y = cvt_pk(v2, v3);
    }
    {
      float v0 = (acc[q][1][0] + b4[q] - mu[1][0]) * rs[1][0] * gA[q] + bB4[q];
      float v1 = (acc[q][1][1] + b4[q] - mu[1][1]) * rs[1][1] * gA[q] + bB4[q];
      float v2 = (acc[q][1][2] + b4[q] - mu[1][2]) * rs[1][2] * gA[q] + bB4[q];
      float v3 = (acc[q][1][3] + b4[q] - mu[1][3]) * rs[1][3] * gA[q] + bB4[q];
      gv.z = cvt_pk(v0, v1);
      gv.w = cvt_pk(v2, v3);
    }
    gioL[q * 256 + t] = gv;   // private slot
  }

  // ---- PH2: ig gate on gate_feats; gioL <- g1 * ioLN ----
  gemmQ(gT, igWf, acc, wv, lane, lr, lh);
#pragma unroll
  for (int q = 0; q < 4; q++) b4[q] = igb[cb + q * 16 + lr];
  statsW(acc, b4, sP[0], qP[0], wv, lr, lh);
  {
    uint4 gv[4];
#pragma unroll
    for (int q = 0; q < 4; q++) gv[q] = gioL[q * 256 + t];   // own slots (pre-barrier OK)
    __syncthreads();   // S3
    statsR(sP[0], qP[0], mu, rs, lh);
#pragma unroll
    for (int q = 0; q < 4; q++) { gA[q] = iig[cb + q * 16 + lr]; bB4[q] = iib[cb + q * 16 + lr]; }
#pragma unroll
    for (int q = 0; q < 4; q++) {
      float v[2][4];
#pragma unroll
      for (int rh = 0; rh < 2; rh++)
#pragma unroll
        for (int i = 0; i < 4; i++) {
          float p = (acc[q][rh][i] + b4[q] - mu[rh][i]) * rs[rh][i] * gA[q] + bB4[q];
          float g1 = 1.f / (1.f + __expf(-p));
          v[rh][i] = g1 * bhalf(gsel(gv[q], rh, i >> 1), i & 1);
        }
      uint4 nv;
      nv.x = cvt_pk(v[0][0], v[0][1]);
      nv.y = cvt_pk(v[0][2], v[0][3]);
      nv.z = cvt_pk(v[1][0], v[1][1]);
      nv.w = cvt_pk(v[1][2], v[1][3]);
      gioL[q * 256 + t] = nv;
    }
  }

  // ---- PH3: ug gate; features = g2*param_out_ln + gio -> aT (pi-layout) ----
  gemmQ(gT, ugWf, acc, wv, lane, lr, lh);
#pragma unroll
  for (int q = 0; q < 4; q++) b4[q] = ugb[cb + q * 16 + lr];
  statsW(acc, b4, sP[1], qP[1], wv, lr, lh);
  {
    uint4 gv[4];
#pragma unroll
    for (int q = 0; q < 4; q++) gv[q] = gioL[q * 256 + t];   // load BEFORE S4: after the
    __syncthreads();   // S4                                  // barrier, features writes
    statsR(sP[1], qP[1], mu, rs, lh);                         // may clobber gioL region
#pragma unroll
    for (int q = 0; q < 4; q++) { gA[q] = nig[cb + q * 16 + lr]; bB4[q] = nib[cb + q * 16 + lr]; }
#pragma unroll
    for (int rh = 0; rh < 2; rh++)
#pragma unroll
      for (int i = 0; i < 4; i++) {
        const int rr = rh * 16 + lh * 4 + i;
        const float* po = param_out_ln + (size_t)div9(r0 + rr) * 256;
        float ft[4];
#pragma unroll
        for (int q = 0; q < 4; q++) {
          float u = (acc[q][rh][i] + b4[q] - mu[rh][i]) * rs[rh][i] * gA[q] + bB4[q];
          float g2 = 1.f / (1.f + __expf(-u));
          ft[q] = g2 * po[cb + q * 16 + lr] + bhalf(gsel(gv[q], rh, i >> 1), i & 1);
        }
        uint2 pk;
        pk.x = cvt_pk(ft[0], ft[1]);
        pk.y = cvt_pk(ft[2], ft[3]);
        *(uint2*)&aT[rr * APITCH + cb + lr * 4] = pk;   // pi position
      }
  }
  __syncthreads();   // S5: aT(features, pi-layout) ready

  // ---- PH4: fc (pi-permuted weights), LN, relu -> out ----
  gemmQ(aT, fcWf, acc, wv, lane, lr, lh);
#pragma unroll
  for (int q = 0; q < 4; q++) b4[q] = fcb[cb + q * 16 + lr];
  statsW(acc, b4, sP[0], qP[0], wv, lr, lh);
  __syncthreads();
  statsR(sP[0], qP[0], mu, rs, lh);
#pragma unroll
  for (int q = 0; q < 4; q++) { gA[q] = fng[cb + q * 16 + lr]; bB4[q] = fnb[cb + q * 16 + lr]; }
#pragma unroll
  for (int q = 0; q < 4; q++) {
    const int col = cb + q * 16 + lr;
#pragma unroll
    for (int rh = 0; rh < 2; rh++)
#pragma unroll
      for (int i = 0; i < 4; i++) {
        float v = (acc[q][rh][i] + b4[q] - mu[rh][i]) * rs[rh][i] * gA[q] + bB4[q];
        out[(size_t)(r0 + rh * 16 + lh * 4 + i) * 256 + col] = fmaxf(v, 0.f);
      }
  }
}

// ================= kernel 1: params (unchanged) =================
#define FPITCH 516

__device__ __forceinline__ void red8(float& s, float& q) {
#pragma unroll
  for (int m = 1; m < 8; m <<= 1) { s += __shfl_xor(s, m); q += __shfl_xor(q, m); }
}

__global__ __launch_bounds__(256) void k_params(
    const float* __restrict__ uf, const unsigned short* __restrict__ dynWf,
    const float* __restrict__ dynb, const float* __restrict__ nog,
    const float* __restrict__ nob, float* __restrict__ param_in,
    float* __restrict__ param_out_ln) {
  __shared__ short aT[32 * APITCH];
  __shared__ float fBuf[32 * FPITCH];
  const int t = threadIdx.x;
  const int wv = t >> 6, lane = t & 63, lr = lane & 15, lh = lane >> 4;
  const int r0 = blockIdx.x * 32;
#pragma unroll
  for (int j = 0; j < 8; j++) {
    const int idx4 = j * 256 + t;
    const int row = idx4 >> 6;
    const int c4 = (idx4 & 63) << 2;
    const float4 v = *(const float4*)&uf[(size_t)(r0 + row) * 256 + c4];
    uint2 pk;
    pk.x = cvt_pk(v.x, v.y);
    pk.y = cvt_pk(v.z, v.w);
    *(uint2*)&aT[row * APITCH + c4] = pk;
  }
  __syncthreads();
  bf16x8 a0[8], a1[8];
#pragma unroll
  for (int kk = 0; kk < 8; kk++) {
    a0[kk] = *(const bf16x8*)&aT[lr * APITCH + kk * 32 + lh * 8];
    a1[kk] = *(const bf16x8*)&aT[(16 + lr) * APITCH + kk * 32 + lh * 8];
  }
#pragma unroll 1
  for (int cp = 0; cp < 8; cp++) {
    const int ct = wv * 8 + cp;
    bf16x8 b[8];
#pragma unroll
    for (int kk = 0; kk < 8; kk++)
      b[kk] = *(const bf16x8*)&dynWf[((ct * 8 + kk) * 64 + lane) * 8];
    const float bi = dynb[ct * 16 + lr];
    f32x4 c0 = {0.f, 0.f, 0.f, 0.f}, c1 = c0;
#pragma unroll
    for (int kk = 0; kk < 8; kk++) {
      c0 = __builtin_amdgcn_mfma_f32_16x16x32_bf16(a0[kk], b[kk], c0, 0, 0, 0);
      c1 = __builtin_amdgcn_mfma_f32_16x16x32_bf16(a1[kk], b[kk], c1, 0, 0, 0);
    }
#pragma unroll
    for (int i = 0; i < 4; i++) {
      fBuf[(lh * 4 + i) * FPITCH + ct * 16 + lr] = c0[i] + bi;
      fBuf[(16 + lh * 4 + i) * FPITCH + ct * 16 + lr] = c1[i] + bi;
    }
  }
  __syncthreads();
  const int row = t >> 3, j = t & 7;
  float s = 0.f, q = 0.f;
#pragma unroll
  for (int i = 0; i < 32; i++) {
    float x = fBuf[row * FPITCH + 256 + j + 8 * i];
    s += x; q += x * x;
  }
  red8(s, q);
  const float mu = s * (1.f / 256.f);
  const float rsv = rsqrtf(q * (1.f / 256.f) - mu * mu + EPS);
#pragma unroll 1
  for (int i = 0; i < 32; i++) {
    const int c = j + 8 * i;
    float x = fBuf[row * FPITCH + 256 + c];
    param_out_ln[(size_t)(r0 + row) * 256 + c] = (x - mu) * rsv * nog[c] + nob[c];
  }
#pragma unroll
  for (int jj = 0; jj < 8; jj++) {
    const int idx4 = jj * 256 + t;
    const int rwq = idx4 >> 6;
    const int c4 = (idx4 & 63) << 2;
    float4 v;
    v.x = fBuf[rwq * FPITCH + c4 + 0];
    v.y = fBuf[rwq * FPITCH + c4 + 1];
    v.z = fBuf[rwq * FPITCH + c4 + 2];
    v.w = fBuf[rwq * FPITCH + c4 + 3];
    *(float4*)&param_in[(size_t)(r0 + rwq) * 256 + c4] = v;
  }
}

extern "C" void kernel_launch(void* const* d_in, const int* in_sizes, int n_in,
                              void* d_out, int out_size, void* d_ws, size_t ws_size,
                              hipStream_t stream) {
  const float* uf   = (const float*)d_in[0];
  const float* inf  = (const float*)d_in[1];
  const float* dynW = (const float*)d_in[2];
  const float* dynb = (const float*)d_in[3];
  const float* inpW = (const float*)d_in[4];
  const float* inpb = (const float*)d_in[5];
  const float* igW  = (const float*)d_in[6];
  const float* igb  = (const float*)d_in[7];
  const float* ugW  = (const float*)d_in[8];
  const float* ugb  = (const float*)d_in[9];
  const float* fcW  = (const float*)d_in[10];
  const float* fcb  = (const float*)d_in[11];
  const float* nig  = (const float*)d_in[12];
  const float* nib  = (const float*)d_in[13];
  const float* nog  = (const float*)d_in[14];
  const float* nob  = (const float*)d_in[15];
  const float* iig  = (const float*)d_in[16];
  const float* iib  = (const float*)d_in[17];
  const float* iog  = (const float*)d_in[18];
  const float* iob  = (const float*)d_in[19];
  const float* fng  = (const float*)d_in[20];
  const float* fnb  = (const float*)d_in[21];
  float* out = (float*)d_out;

  char* ws = (char*)d_ws;
  unsigned short* Wf = (unsigned short*)ws;
  unsigned short* dynWf = Wf;
  unsigned short* inpWf = Wf + 131072;
  unsigned short* igWf  = Wf + 262144;
  unsigned short* ugWf  = Wf + 327680;
  unsigned short* fcWf  = Wf + 393216;
  float* param_in     = (float*)(ws + (1 << 20));
  float* param_out_ln = (float*)(ws + (1 << 20) + (16 << 20));

  k_cvt_all<<<dim3(1792), dim3(256), 0, stream>>>(dynW, inpW, igW, ugW, fcW, Wf);

  k_params<<<dim3(512), dim3(256), 0, stream>>>(uf, dynWf, dynb, nog, nob,
                                                param_in, param_out_ln);

  k_main<<<dim3(4608), dim3(256), 0, stream>>>(
      inf, inpWf, inpb, igWf, igb, ugWf, ugb, fcWf, fcb,
      nig, nib, iig, iib, iog, iob, fng, fnb,
      param_in, param_out_ln, out);
}

// Round 13
// 295.245 us; speedup vs baseline: 1.0004x; 1.0004x over previous
//
#include <hip/hip_runtime.h>

#define EPS 1e-5f
#define APITCH 264   // bf16 tile row pitch (shorts); 528B rows, 16B-aligned

typedef __attribute__((ext_vector_type(8))) short bf16x8;
typedef __attribute__((ext_vector_type(4))) float f32x4;

// RTNE (one-time weight conversion)
__device__ __forceinline__ unsigned short f2b_rtne(float f) {
  unsigned u = __builtin_bit_cast(unsigned, f);
  u += 0x7fffu + ((u >> 16) & 1u);
  return (unsigned short)(u >> 16);
}
// HW packed f32->2xbf16 (RTNE)
__device__ __forceinline__ unsigned cvt_pk(float lo, float hi) {
  unsigned r;
  asm("v_cvt_pk_bf16_f32 %0, %1, %2" : "=v"(r) : "v"(lo), "v"(hi));
  return r;
}
__device__ __forceinline__ float bhalf(unsigned pk, int hi) {
  unsigned u = hi ? (pk & 0xffff0000u) : (pk << 16);
  return __builtin_bit_cast(float, u);
}
__device__ __forceinline__ int div9(int r) {
  return (int)(__umulhi((unsigned)r, 954437177u) >> 1);
}

// Convert all 5 weight matrices into MFMA-fragment-linear bf16 (contiguous dst).
// ig/ug/fc k-index pre-permuted for the pi-packed LDS tiles:
//   pi: col = cb + q*16 + lr  ->  p = cb + lr*4 + q  (within each 64-col block)
__global__ void k_cvt_all(const float* __restrict__ dynW, const float* __restrict__ inpW,
                          const float* __restrict__ igW, const float* __restrict__ ugW,
                          const float* __restrict__ fcW, unsigned short* __restrict__ dst) {
  int i = blockIdx.x * blockDim.x + threadIdx.x;   // [0, 458752)
  const float* src; int off; int perm;
  if (i < 131072)      { src = dynW; off = i;          perm = 0; }
  else if (i < 262144) { src = inpW; off = i - 131072; perm = 0; }
  else if (i < 327680) { src = igW;  off = i - 262144; perm = 1; }
  else if (i < 393216) { src = ugW;  off = i - 327680; perm = 1; }
  else                 { src = fcW;  off = i - 393216; perm = 1; }
  int j = off & 7, lane = (off >> 3) & 63, kk = (off >> 9) & 7, ct = off >> 12;
  int row = ct * 16 + (lane & 15);
  int p = kk * 32 + (lane >> 4) * 8 + j;           // k position in fragment order
  int col = perm ? ((p & ~63) + (p & 3) * 16 + ((p >> 2) & 15)) : p;
  dst[i] = f2b_rtne(src[row * 256 + col]);
}

// ================= 32-row main kernel, single-tile LDS (18.9KB -> 8 blocks/CU) =======
// gT eliminated: gate_feats held in 16 regs (gReg) across PH1, then written INTO aT
// after S2 (all aT gemm-reads complete). PH3 features likewise overwrite aT after S5.
// Burst structure (b[8] -> 16 MFMA, a re-read per q) unchanged (R10: splitting = -33%).
// gio stays in registers (R12: LDS round-trip cost ~15us).

__device__ __forceinline__ void gemmQ(const short* src,
                                      const unsigned short* __restrict__ W,
                                      f32x4 (&acc)[4][2],
                                      int wv, int lane, int lr, int lh) {
#pragma unroll
  for (int q = 0; q < 4; q++) {
    const unsigned short* Wp = W + ((wv * 4 + q) << 12) + lane * 8;
    bf16x8 b[8];
#pragma unroll
    for (int kk = 0; kk < 8; kk++) b[kk] = *(const bf16x8*)&Wp[kk * 512];
    int zoff = 0;
    asm volatile("" : "+v"(zoff));          // opaque 0: forces a re-read each q
    const short* ap = src + zoff;
    bf16x8 a[8];
#pragma unroll
    for (int kk = 0; kk < 8; kk++)
      a[kk] = *(const bf16x8*)&ap[lr * APITCH + kk * 32 + lh * 8];
    acc[q][0] = (f32x4){0.f, 0.f, 0.f, 0.f};
#pragma unroll
    for (int kk = 0; kk < 8; kk++)
      acc[q][0] = __builtin_amdgcn_mfma_f32_16x16x32_bf16(a[kk], b[kk], acc[q][0], 0, 0, 0);
#pragma unroll
    for (int kk = 0; kk < 8; kk++)
      a[kk] = *(const bf16x8*)&ap[(16 + lr) * APITCH + kk * 32 + lh * 8];
    acc[q][1] = (f32x4){0.f, 0.f, 0.f, 0.f};
#pragma unroll
    for (int kk = 0; kk < 8; kk++)
      acc[q][1] = __builtin_amdgcn_mfma_f32_16x16x32_bf16(a[kk], b[kk], acc[q][1], 0, 0, 0);
  }
}

__device__ __forceinline__ void statsW(const f32x4 (&acc)[4][2], const float (&b4)[4],
                                       float* sP, float* qP, int wv, int lr, int lh) {
#pragma unroll
  for (int rh = 0; rh < 2; rh++)
#pragma unroll
    for (int i = 0; i < 4; i++) {
      float s = 0.f, qq = 0.f;
#pragma unroll
      for (int q = 0; q < 4; q++) { float v = acc[q][rh][i] + b4[q]; s += v; qq += v * v; }
#pragma unroll
      for (int m = 1; m < 16; m <<= 1) { s += __shfl_xor(s, m); qq += __shfl_xor(qq, m); }
      if (lr == 0) {
        int r = rh * 16 + lh * 4 + i;
        sP[wv * 32 + r] = s; qP[wv * 32 + r] = qq;
      }
    }
}
__device__ __forceinline__ void statsR(const float* sP, const float* qP,
                                       float (&mu)[2][4], float (&rs)[2][4], int lh) {
#pragma unroll
  for (int rh = 0; rh < 2; rh++)
#pragma unroll
    for (int i = 0; i < 4; i++) {
      int r = rh * 16 + lh * 4 + i;
      float S = sP[r] + sP[32 + r] + sP[64 + r] + sP[96 + r];
      float Q = qP[r] + qP[32 + r] + qP[64 + r] + qP[96 + r];
      float m = S * (1.f / 256.f);
      mu[rh][i] = m;
      rs[rh][i] = rsqrtf(Q * (1.f / 256.f) - m * m + EPS);
    }
}

// NOTE: no min-waves arg — a second __launch_bounds__ argument caps arch-VGPR at
// 256/minwaves on MFMA kernels (observed R2-R4) and forces scratch.
__global__ __launch_bounds__(256) void k_main(
    const float* __restrict__ inf,
    const unsigned short* __restrict__ inpWf, const float* __restrict__ inpb,
    const unsigned short* __restrict__ igWf, const float* __restrict__ igb,
    const unsigned short* __restrict__ ugWf, const float* __restrict__ ugb,
    const unsigned short* __restrict__ fcWf, const float* __restrict__ fcb,
    const float* __restrict__ nig, const float* __restrict__ nib,
    const float* __restrict__ iig, const float* __restrict__ iib,
    const float* __restrict__ iog, const float* __restrict__ iob,
    const float* __restrict__ fng, const float* __restrict__ fnb,
    const float* __restrict__ param_in, const float* __restrict__ param_out_ln,
    float* __restrict__ out) {
  __shared__ short aT[32 * APITCH];            // input -> gate_feats -> features
  __shared__ float sP[2][128], qP[2][128];     // total LDS = 16896 + 2048 = 18944B

  const int t = threadIdx.x;
  const int wv = t >> 6, lane = t & 63, lr = lane & 15, lh = lane >> 4;
  const int cb = wv * 64;
  const int r0 = blockIdx.x * 32;

  // stage 32x256 f32 -> bf16 LDS (coalesced float4 in, packed b64 out)
#pragma unroll
  for (int j = 0; j < 8; j++) {
    const int idx4 = j * 256 + t;
    const int row = idx4 >> 6;
    const int c4 = (idx4 & 63) << 2;
    const float4 v = *(const float4*)&inf[(size_t)(r0 + row) * 256 + c4];
    uint2 pk;
    pk.x = cvt_pk(v.x, v.y);
    pk.y = cvt_pk(v.z, v.w);
    *(uint2*)&aT[row * APITCH + c4] = pk;
  }
  __syncthreads();                             // S1

  f32x4 acc[4][2];
  float b4[4], mu[2][4], rs[2][4], gA[4], bB4[4];
  unsigned gio[4][2][2];     // packed bf16 pairs per (q, rh)
  unsigned gReg[2][4][2];    // gate_feats packed per (rh, i): 2 words of 4 q-vals

  // ---- PH0: input_in -> gate_feats -> gReg (registers) ----
  gemmQ(aT, inpWf, acc, wv, lane, lr, lh);
#pragma unroll
  for (int q = 0; q < 4; q++) b4[q] = inpb[cb + q * 16 + lr];
#pragma unroll
  for (int rh = 0; rh < 2; rh++)
#pragma unroll
    for (int i = 0; i < 4; i++) {
      const int rr = rh * 16 + lh * 4 + i;
      const float* pin = param_in + (size_t)div9(r0 + rr) * 256;
      float g[4];
#pragma unroll
      for (int q = 0; q < 4; q++)
        g[q] = (acc[q][rh][i] + b4[q]) * pin[cb + q * 16 + lr];
      gReg[rh][i][0] = cvt_pk(g[0], g[1]);
      gReg[rh][i][1] = cvt_pk(g[2], g[3]);
    }

  // ---- PH1: input_out (reads aT), LN -> gio ----
  gemmQ(aT, inpWf + (16 << 12), acc, wv, lane, lr, lh);
#pragma unroll
  for (int q = 0; q < 4; q++) b4[q] = inpb[256 + cb + q * 16 + lr];
  statsW(acc, b4, sP[1], qP[1], wv, lr, lh);
  __syncthreads();                             // S2: ALL aT gemm-reads complete

  // gate_feats -> aT in-place (pi-packed 8B stores); gReg dies here
#pragma unroll
  for (int rh = 0; rh < 2; rh++)
#pragma unroll
    for (int i = 0; i < 4; i++) {
      const int rr = rh * 16 + lh * 4 + i;
      uint2 pk;
      pk.x = gReg[rh][i][0];
      pk.y = gReg[rh][i][1];
      *(uint2*)&aT[rr * APITCH + cb + lr * 4] = pk;
    }
  statsR(sP[1], qP[1], mu, rs, lh);
#pragma unroll
  for (int q = 0; q < 4; q++) { gA[q] = iog[cb + q * 16 + lr]; bB4[q] = iob[cb + q * 16 + lr]; }
#pragma unroll
  for (int q = 0; q < 4; q++) {
#pragma unroll
    for (int rh = 0; rh < 2; rh++) {
      float v0 = (acc[q][rh][0] + b4[q] - mu[rh][0]) * rs[rh][0] * gA[q] + bB4[q];
      float v1 = (acc[q][rh][1] + b4[q] - mu[rh][1]) * rs[rh][1] * gA[q] + bB4[q];
      float v2 = (acc[q][rh][2] + b4[q] - mu[rh][2]) * rs[rh][2] * gA[q] + bB4[q];
      float v3 = (acc[q][rh][3] + b4[q] - mu[rh][3]) * rs[rh][3] * gA[q] + bB4[q];
      gio[q][rh][0] = cvt_pk(v0, v1);
      gio[q][rh][1] = cvt_pk(v2, v3);
    }
  }
  __syncthreads();                             // S3: gate_feats published in aT

  // ---- PH2: ig gate on aT(gate); gio <- g1 * ioLN ----
  gemmQ(aT, igWf, acc, wv, lane, lr, lh);
#pragma unroll
  for (int q = 0; q < 4; q++) b4[q] = igb[cb + q * 16 + lr];
  statsW(acc, b4, sP[0], qP[0], wv, lr, lh);
  __syncthreads();                             // S4
  statsR(sP[0], qP[0], mu, rs, lh);
#pragma unroll
  for (int q = 0; q < 4; q++) { gA[q] = iig[cb + q * 16 + lr]; bB4[q] = iib[cb + q * 16 + lr]; }
#pragma unroll
  for (int q = 0; q < 4; q++) {
#pragma unroll
    for (int rh = 0; rh < 2; rh++) {
      float v[4];
#pragma unroll
      for (int i = 0; i < 4; i++) {
        float p = (acc[q][rh][i] + b4[q] - mu[rh][i]) * rs[rh][i] * gA[q] + bB4[q];
        float g1 = 1.f / (1.f + __expf(-p));
        v[i] = g1 * bhalf(gio[q][rh][i >> 1], i & 1);
      }
      gio[q][rh][0] = cvt_pk(v[0], v[1]);
      gio[q][rh][1] = cvt_pk(v[2], v[3]);
    }
  }

  // ---- PH3: ug gate on aT(gate); features -> aT (pi) ----
  gemmQ(aT, ugWf, acc, wv, lane, lr, lh);
#pragma unroll
  for (int q = 0; q < 4; q++) b4[q] = ugb[cb + q * 16 + lr];
  statsW(acc, b4, sP[1], qP[1], wv, lr, lh);
  __syncthreads();                             // S5: ALL gate gemm-reads complete
  statsR(sP[1], qP[1], mu, rs, lh);
#pragma unroll
  for (int q = 0; q < 4; q++) { gA[q] = nig[cb + q * 16 + lr]; bB4[q] = nib[cb + q * 16 + lr]; }
#pragma unroll
  for (int rh = 0; rh < 2; rh++)
#pragma unroll
    for (int i = 0; i < 4; i++) {
      const int rr = rh * 16 + lh * 4 + i;
      const float* po = param_out_ln + (size_t)div9(r0 + rr) * 256;
      float ft[4];
#pragma unroll
      for (int q = 0; q < 4; q++) {
        float u = (acc[q][rh][i] + b4[q] - mu[rh][i]) * rs[rh][i] * gA[q] + bB4[q];
        float g2 = 1.f / (1.f + __expf(-u));
        ft[q] = g2 * po[cb + q * 16 + lr] + bhalf(gio[q][rh][i >> 1], i & 1);
      }
      uint2 pk;
      pk.x = cvt_pk(ft[0], ft[1]);
      pk.y = cvt_pk(ft[2], ft[3]);
      *(uint2*)&aT[rr * APITCH + cb + lr * 4] = pk;
    }
  __syncthreads();                             // S6: features published in aT

  // ---- PH4: fc (pi-permuted weights), LN, relu -> out ----
  gemmQ(aT, fcWf, acc, wv, lane, lr, lh);
#pragma unroll
  for (int q = 0; q < 4; q++) b4[q] = fcb[cb + q * 16 + lr];
  statsW(acc, b4, sP[0], qP[0], wv, lr, lh);
  __syncthreads();                             // S7
  statsR(sP[0], qP[0], mu, rs, lh);
#pragma unroll
  for (int q = 0; q < 4; q++) { gA[q] = fng[cb + q * 16 + lr]; bB4[q] = fnb[cb + q * 16 + lr]; }
#pragma unroll
  for (int q = 0; q < 4; q++) {
    const int col = cb + q * 16 + lr;
#pragma unroll
    for (int rh = 0; rh < 2; rh++)
#pragma unroll
      for (int i = 0; i < 4; i++) {
        float v = (acc[q][rh][i] + b4[q] - mu[rh][i]) * rs[rh][i] * gA[q] + bB4[q];
        out[(size_t)(r0 + rh * 16 + lh * 4 + i) * 256 + col] = fmaxf(v, 0.f);
      }
  }
}

// ================= kernel 1: params (unchanged) =================
#define FPITCH 516

__device__ __forceinline__ void red8(float& s, float& q) {
#pragma unroll
  for (int m = 1; m < 8; m <<= 1) { s += __shfl_xor(s, m); q += __shfl_xor(q, m); }
}

__global__ __launch_bounds__(256) void k_params(
    const float* __restrict__ uf, const unsigned short* __restrict__ dynWf,
    const float* __restrict__ dynb, const float* __restrict__ nog,
    const float* __restrict__ nob, float* __restrict__ param_in,
    float* __restrict__ param_out_ln) {
  __shared__ short aT[32 * APITCH];
  __shared__ float fBuf[32 * FPITCH];
  const int t = threadIdx.x;
  const int wv = t >> 6, lane = t & 63, lr = lane & 15, lh = lane >> 4;
  const int r0 = blockIdx.x * 32;
#pragma unroll
  for (int j = 0; j < 8; j++) {
    const int idx4 = j * 256 + t;
    const int row = idx4 >> 6;
    const int c4 = (idx4 & 63) << 2;
    const float4 v = *(const float4*)&uf[(size_t)(r0 + row) * 256 + c4];
    uint2 pk;
    pk.x = cvt_pk(v.x, v.y);
    pk.y = cvt_pk(v.z, v.w);
    *(uint2*)&aT[row * APITCH + c4] = pk;
  }
  __syncthreads();
  bf16x8 a0[8], a1[8];
#pragma unroll
  for (int kk = 0; kk < 8; kk++) {
    a0[kk] = *(const bf16x8*)&aT[lr * APITCH + kk * 32 + lh * 8];
    a1[kk] = *(const bf16x8*)&aT[(16 + lr) * APITCH + kk * 32 + lh * 8];
  }
#pragma unroll 1
  for (int cp = 0; cp < 8; cp++) {
    const int ct = wv * 8 + cp;
    bf16x8 b[8];
#pragma unroll
    for (int kk = 0; kk < 8; kk++)
      b[kk] = *(const bf16x8*)&dynWf[((ct * 8 + kk) * 64 + lane) * 8];
    const float bi = dynb[ct * 16 + lr];
    f32x4 c0 = {0.f, 0.f, 0.f, 0.f}, c1 = c0;
#pragma unroll
    for (int kk = 0; kk < 8; kk++) {
      c0 = __builtin_amdgcn_mfma_f32_16x16x32_bf16(a0[kk], b[kk], c0, 0, 0, 0);
      c1 = __builtin_amdgcn_mfma_f32_16x16x32_bf16(a1[kk], b[kk], c1, 0, 0, 0);
    }
#pragma unroll
    for (int i = 0; i < 4; i++) {
      fBuf[(lh * 4 + i) * FPITCH + ct * 16 + lr] = c0[i] + bi;
      fBuf[(16 + lh * 4 + i) * FPITCH + ct * 16 + lr] = c1[i] + bi;
    }
  }
  __syncthreads();
  const int row = t >> 3, j = t & 7;
  float s = 0.f, q = 0.f;
#pragma unroll
  for (int i = 0; i < 32; i++) {
    float x = fBuf[row * FPITCH + 256 + j + 8 * i];
    s += x; q += x * x;
  }
  red8(s, q);
  const float mu = s * (1.f / 256.f);
  const float rsv = rsqrtf(q * (1.f / 256.f) - mu * mu + EPS);
#pragma unroll 1
  for (int i = 0; i < 32; i++) {
    const int c = j + 8 * i;
    float x = fBuf[row * FPITCH + 256 + c];
    param_out_ln[(size_t)(r0 + row) * 256 + c] = (x - mu) * rsv * nog[c] + nob[c];
  }
#pragma unroll
  for (int jj = 0; jj < 8; jj++) {
    const int idx4 = jj * 256 + t;
    const int rwq = idx4 >> 6;
    const int c4 = (idx4 & 63) << 2;
    float4 v;
    v.x = fBuf[rwq * FPITCH + c4 + 0];
    v.y = fBuf[rwq * FPITCH + c4 + 1];
    v.z = fBuf[rwq * FPITCH + c4 + 2];
    v.w = fBuf[rwq * FPITCH + c4 + 3];
    *(float4*)&param_in[(size_t)(r0 + rwq) * 256 + c4] = v;
  }
}

extern "C" void kernel_launch(void* const* d_in, const int* in_sizes, int n_in,
                              void* d_out, int out_size, void* d_ws, size_t ws_size,
                              hipStream_t stream) {
  const float* uf   = (const float*)d_in[0];
  const float* inf  = (const float*)d_in[1];
  const float* dynW = (const float*)d_in[2];
  const float* dynb = (const float*)d_in[3];
  const float* inpW = (const float*)d_in[4];
  const float* inpb = (const float*)d_in[5];
  const float* igW  = (const float*)d_in[6];
  const float* igb  = (const float*)d_in[7];
  const float* ugW  = (const float*)d_in[8];
  const float* ugb  = (const float*)d_in[9];
  const float* fcW  = (const float*)d_in[10];
  const float* fcb  = (const float*)d_in[11];
  const float* nig  = (const float*)d_in[12];
  const float* nib  = (const float*)d_in[13];
  const float* nog  = (const float*)d_in[14];
  const float* nob  = (const float*)d_in[15];
  const float* iig  = (const float*)d_in[16];
  const float* iib  = (const float*)d_in[17];
  const float* iog  = (const float*)d_in[18];
  const float* iob  = (const float*)d_in[19];
  const float* fng  = (const float*)d_in[20];
  const float* fnb  = (const float*)d_in[21];
  float* out = (float*)d_out;

  char* ws = (char*)d_ws;
  unsigned short* Wf = (unsigned short*)ws;
  unsigned short* dynWf = Wf;
  unsigned short* inpWf = Wf + 131072;
  unsigned short* igWf  = Wf + 262144;
  unsigned short* ugWf  = Wf + 327680;
  unsigned short* fcWf  = Wf + 393216;
  float* param_in     = (float*)(ws + (1 << 20));
  float* param_out_ln = (float*)(ws + (1 << 20) + (16 << 20));

  k_cvt_all<<<dim3(1792), dim3(256), 0, stream>>>(dynW, inpW, igW, ugW, fcW, Wf);

  k_params<<<dim3(512), dim3(256), 0, stream>>>(uf, dynWf, dynb, nog, nob,
                                                param_in, param_out_ln);

  k_main<<<dim3(4608), dim3(256), 0, stream>>>(
      inf, inpWf, inpb, igWf, igb, ugWf, ugb, fcWf, fcb,
      nig, nib, iig, iib, iog, iob, fng, fnb,
      param_in, param_out_ln, out);
}

// Round 15
// 269.529 us; speedup vs baseline: 1.0959x; 1.0954x over previous
//
#include <hip/hip_runtime.h>

#define EPS 1e-5f
#define APITCH 264   // bf16 tile row pitch (shorts); 528B rows, 16B-aligned

typedef __attribute__((ext_vector_type(8))) short bf16x8;
typedef __attribute__((ext_vector_type(4))) float f32x4;
typedef __attribute__((ext_vector_type(2))) float f32x2;

// RTNE (one-time weight conversion)
__device__ __forceinline__ unsigned short f2b_rtne(float f) {
  unsigned u = __builtin_bit_cast(unsigned, f);
  u += 0x7fffu + ((u >> 16) & 1u);
  return (unsigned short)(u >> 16);
}
// HW packed f32->2xbf16 (RTNE)
__device__ __forceinline__ unsigned cvt_pk(float lo, float hi) {
  unsigned r;
  asm("v_cvt_pk_bf16_f32 %0, %1, %2" : "=v"(r) : "v"(lo), "v"(hi));
  return r;
}
__device__ __forceinline__ float bhalf(unsigned pk, int hi) {
  unsigned u = hi ? (pk & 0xffff0000u) : (pk << 16);
  return __builtin_bit_cast(float, u);
}
__device__ __forceinline__ int div9(int r) {
  return (int)(__umulhi((unsigned)r, 954437177u) >> 1);
}

// ---- packed f32 math (CDNA dual-FP32 VOP3P) ----
__device__ __forceinline__ f32x2 pk_add(f32x2 a, f32x2 b) {
  f32x2 d; asm("v_pk_add_f32 %0, %1, %2" : "=v"(d) : "v"(a), "v"(b)); return d;
}
__device__ __forceinline__ f32x2 pk_mul(f32x2 a, f32x2 b) {
  f32x2 d; asm("v_pk_mul_f32 %0, %1, %2" : "=v"(d) : "v"(a), "v"(b)); return d;
}
__device__ __forceinline__ f32x2 pk_fma(f32x2 a, f32x2 b, f32x2 c) {
  f32x2 d; asm("v_pk_fma_f32 %0, %1, %2, %3" : "=v"(d) : "v"(a), "v"(b), "v"(c)); return d;
}
__device__ __forceinline__ f32x2 ld2(const float* p) { return *(const f32x2*)p; }

// ---- DPP 16-lane sum reduction (ctrl must be a literal -> template param) ----
template <int CTRL>
__device__ __forceinline__ float dppadd(float v) {
  int x = __builtin_amdgcn_update_dpp(0, __builtin_bit_cast(int, v), CTRL, 0xf, 0xf, true);
  return v + __builtin_bit_cast(float, x);
}
__device__ __forceinline__ float dpp_reduce16(float v) {
  v = dppadd<0xB1>(v);    // quad_perm:[1,0,3,2]  (xor 1)
  v = dppadd<0x4E>(v);    // quad_perm:[2,3,0,1]  (xor 2)
  v = dppadd<0x124>(v);   // row_ror:4
  v = dppadd<0x128>(v);   // row_ror:8
  return v;               // every lane in the 16-lane row holds the row sum
}

// Convert all 5 weight matrices into MFMA-fragment-linear bf16 (contiguous dst).
// ig/ug/fc k-index pre-permuted for the pi-packed LDS tiles:
//   pi: col = cb + q*16 + lr  ->  p = cb + lr*4 + q  (within each 64-col block)
__global__ void k_cvt_all(const float* __restrict__ dynW, const float* __restrict__ inpW,
                          const float* __restrict__ igW, const float* __restrict__ ugW,
                          const float* __restrict__ fcW, unsigned short* __restrict__ dst) {
  int i = blockIdx.x * blockDim.x + threadIdx.x;   // [0, 458752)
  const float* src; int off; int perm;
  if (i < 131072)      { src = dynW; off = i;          perm = 0; }
  else if (i < 262144) { src = inpW; off = i - 131072; perm = 0; }
  else if (i < 327680) { src = igW;  off = i - 262144; perm = 1; }
  else if (i < 393216) { src = ugW;  off = i - 327680; perm = 1; }
  else                 { src = fcW;  off = i - 393216; perm = 1; }
  int j = off & 7, lane = (off >> 3) & 63, kk = (off >> 9) & 7, ct = off >> 12;
  int row = ct * 16 + (lane & 15);
  int p = kk * 32 + (lane >> 4) * 8 + j;           // k position in fragment order
  int col = perm ? ((p & ~63) + (p & 3) * 16 + ((p >> 2) & 15)) : p;
  dst[i] = f2b_rtne(src[row * 256 + col]);
}

// ================= 32-row main kernel (R11 structure + DPP stats + pk-f32 LN) =======
// Unified reg budget: ~112 arch + 32 AGPR = 144 total = the residency sweet spot
// (cliff in (144,168]: R9/R11@144->22% occ, R6@168->slow, R5@204->11.8%).
// Burst structure (b[8] -> 16 MFMA, a re-read per q) unchanged (R10: split = -33%).

__device__ __forceinline__ void gemmQ(const short* src,
                                      const unsigned short* __restrict__ W,
                                      f32x4 (&acc)[4][2],
                                      int wv, int lane, int lr, int lh) {
#pragma unroll
  for (int q = 0; q < 4; q++) {
    const unsigned short* Wp = W + ((wv * 4 + q) << 12) + lane * 8;
    bf16x8 b[8];
#pragma unroll
    for (int kk = 0; kk < 8; kk++) b[kk] = *(const bf16x8*)&Wp[kk * 512];
    int zoff = 0;
    asm volatile("" : "+v"(zoff));          // opaque 0: forces a re-read each q
    const short* ap = src + zoff;
    bf16x8 a[8];
#pragma unroll
    for (int kk = 0; kk < 8; kk++)
      a[kk] = *(const bf16x8*)&ap[lr * APITCH + kk * 32 + lh * 8];
    acc[q][0] = (f32x4){0.f, 0.f, 0.f, 0.f};
#pragma unroll
    for (int kk = 0; kk < 8; kk++)
      acc[q][0] = __builtin_amdgcn_mfma_f32_16x16x32_bf16(a[kk], b[kk], acc[q][0], 0, 0, 0);
#pragma unroll
    for (int kk = 0; kk < 8; kk++)
      a[kk] = *(const bf16x8*)&ap[(16 + lr) * APITCH + kk * 32 + lh * 8];
    acc[q][1] = (f32x4){0.f, 0.f, 0.f, 0.f};
#pragma unroll
    for (int kk = 0; kk < 8; kk++)
      acc[q][1] = __builtin_amdgcn_mfma_f32_16x16x32_bf16(a[kk], b[kk], acc[q][1], 0, 0, 0);
  }
}

// per-row (sum, sumsq): pk presum over q, DPP 16-lane reduce, one LDS write per row-pair
__device__ __forceinline__ void statsW(const f32x4 (&acc)[4][2], const f32x2 (&b42)[4],
                                       float* sP, float* qP, int wv, int lr, int lh) {
#pragma unroll
  for (int rh = 0; rh < 2; rh++)
#pragma unroll
    for (int p = 0; p < 2; p++) {
      f32x2 s2 = (f32x2){0.f, 0.f}, q2 = (f32x2){0.f, 0.f};
#pragma unroll
      for (int q = 0; q < 4; q++) {
        f32x2 a2 = (f32x2){acc[q][rh][2 * p], acc[q][rh][2 * p + 1]};
        f32x2 t = pk_add(a2, b42[q]);
        s2 = pk_add(s2, t);
        q2 = pk_fma(t, t, q2);
      }
      float s0 = dpp_reduce16(s2[0]);
      float s1 = dpp_reduce16(s2[1]);
      float q0 = dpp_reduce16(q2[0]);
      float q1 = dpp_reduce16(q2[1]);
      if (lr == 0) {
        int r = rh * 16 + lh * 4 + 2 * p;
        sP[wv * 32 + r] = s0;  sP[wv * 32 + r + 1] = s1;
        qP[wv * 32 + r] = q0;  qP[wv * 32 + r + 1] = q1;
      }
    }
}
// cross-wave combine -> (-mu, rs) pairs
__device__ __forceinline__ void statsR(const float* sP, const float* qP,
                                       f32x2 (&nmu)[2][2], f32x2 (&rv)[2][2], int lh) {
#pragma unroll
  for (int rh = 0; rh < 2; rh++)
#pragma unroll
    for (int p = 0; p < 2; p++) {
      int r = rh * 16 + lh * 4 + 2 * p;
      f32x2 S = pk_add(pk_add(ld2(sP + r), ld2(sP + 32 + r)),
                       pk_add(ld2(sP + 64 + r), ld2(sP + 96 + r)));
      f32x2 Q = pk_add(pk_add(ld2(qP + r), ld2(qP + 32 + r)),
                       pk_add(ld2(qP + 64 + r), ld2(qP + 96 + r)));
      float m0 = S[0] * (1.f / 256.f), m1 = S[1] * (1.f / 256.f);
      nmu[rh][p] = (f32x2){-m0, -m1};
      rv[rh][p] = (f32x2){rsqrtf(Q[0] * (1.f / 256.f) - m0 * m0 + EPS),
                          rsqrtf(Q[1] * (1.f / 256.f) - m1 * m1 + EPS)};
    }
}

// NOTE: no min-waves arg — a second __launch_bounds__ argument caps arch-VGPR at
// 256/minwaves on MFMA kernels (observed R2-R4) and forces scratch.
__global__ __launch_bounds__(256) void k_main(
    const float* __restrict__ inf,
    const unsigned short* __restrict__ inpWf, const float* __restrict__ inpb,
    const unsigned short* __restrict__ igWf, const float* __restrict__ igb,
    const unsigned short* __restrict__ ugWf, const float* __restrict__ ugb,
    const unsigned short* __restrict__ fcWf, const float* __restrict__ fcb,
    const float* __restrict__ nig, const float* __restrict__ nib,
    const float* __restrict__ iig, const float* __restrict__ iib,
    const float* __restrict__ iog, const float* __restrict__ iob,
    const float* __restrict__ fng, const float* __restrict__ fnb,
    const float* __restrict__ param_in, const float* __restrict__ param_out_ln,
    float* __restrict__ out) {
  __shared__ short aT[32 * APITCH];
  __shared__ short gT[32 * APITCH];
  __shared__ float sP[2][128], qP[2][128];

  const int t = threadIdx.x;
  const int wv = t >> 6, lane = t & 63, lr = lane & 15, lh = lane >> 4;
  const int cb = wv * 64;
  const int r0 = blockIdx.x * 32;

  // stage 32x256 f32 -> bf16 LDS (coalesced float4 in, packed b64 out)
#pragma unroll
  for (int j = 0; j < 8; j++) {
    const int idx4 = j * 256 + t;
    const int row = idx4 >> 6;
    const int c4 = (idx4 & 63) << 2;
    const float4 v = *(const float4*)&inf[(size_t)(r0 + row) * 256 + c4];
    uint2 pk;
    pk.x = cvt_pk(v.x, v.y);
    pk.y = cvt_pk(v.z, v.w);
    *(uint2*)&aT[row * APITCH + c4] = pk;
  }
  __syncthreads();                              // S1

  f32x4 acc[4][2];
  f32x2 b42[4], ga2[4], be2[4], nmu[2][2], rv[2][2];
  unsigned gio[4][2][2];   // packed bf16 pairs per (q, pair)

  // ---- PH0: input_in -> gate_feats -> gT (pi-layout, packed 8B writes) ----
  gemmQ(aT, inpWf, acc, wv, lane, lr, lh);
#pragma unroll
  for (int q = 0; q < 4; q++) { float b = inpb[cb + q * 16 + lr]; b42[q] = (f32x2){b, b}; }
#pragma unroll
  for (int rh = 0; rh < 2; rh++)
#pragma unroll
    for (int p = 0; p < 2; p++) {
      const int rrA = rh * 16 + lh * 4 + 2 * p;
      const float* pin0 = param_in + (size_t)div9(r0 + rrA) * 256;
      const float* pin1 = param_in + (size_t)div9(r0 + rrA + 1) * 256;
      float gAv[4], gBv[4];
#pragma unroll
      for (int q = 0; q < 4; q++) {
        f32x2 a2 = (f32x2){acc[q][rh][2 * p], acc[q][rh][2 * p + 1]};
        f32x2 tt = pk_add(a2, b42[q]);
        gAv[q] = tt[0] * pin0[cb + q * 16 + lr];
        gBv[q] = tt[1] * pin1[cb + q * 16 + lr];
      }
      uint2 pkA, pkB;
      pkA.x = cvt_pk(gAv[0], gAv[1]); pkA.y = cvt_pk(gAv[2], gAv[3]);
      pkB.x = cvt_pk(gBv[0], gBv[1]); pkB.y = cvt_pk(gBv[2], gBv[3]);
      *(uint2*)&gT[rrA * APITCH + cb + lr * 4] = pkA;
      *(uint2*)&gT[(rrA + 1) * APITCH + cb + lr * 4] = pkB;
    }

  // ---- PH1: input_out, LN -> gio ----
  gemmQ(aT, inpWf + (16 << 12), acc, wv, lane, lr, lh);
#pragma unroll
  for (int q = 0; q < 4; q++) { float b = inpb[256 + cb + q * 16 + lr]; b42[q] = (f32x2){b, b}; }
  statsW(acc, b42, sP[1], qP[1], wv, lr, lh);
  __syncthreads();                              // S2: gT + stats published
  statsR(sP[1], qP[1], nmu, rv, lh);
#pragma unroll
  for (int q = 0; q < 4; q++) {
    float g = iog[cb + q * 16 + lr], e = iob[cb + q * 16 + lr];
    ga2[q] = (f32x2){g, g}; be2[q] = (f32x2){e, e};
  }
#pragma unroll
  for (int q = 0; q < 4; q++)
#pragma unroll
    for (int rh = 0; rh < 2; rh++)
#pragma unroll
      for (int p = 0; p < 2; p++) {
        f32x2 a2 = (f32x2){acc[q][rh][2 * p], acc[q][rh][2 * p + 1]};
        f32x2 tt = pk_add(pk_add(a2, b42[q]), nmu[rh][p]);
        f32x2 v2 = pk_fma(pk_mul(tt, rv[rh][p]), ga2[q], be2[q]);
        gio[q][rh][p] = cvt_pk(v2[0], v2[1]);
      }

  // ---- PH2: ig gate on gT; gio <- g1 * ioLN ----
  gemmQ(gT, igWf, acc, wv, lane, lr, lh);
#pragma unroll
  for (int q = 0; q < 4; q++) { float b = igb[cb + q * 16 + lr]; b42[q] = (f32x2){b, b}; }
  statsW(acc, b42, sP[0], qP[0], wv, lr, lh);
  __syncthreads();                              // S3
  statsR(sP[0], qP[0], nmu, rv, lh);
#pragma unroll
  for (int q = 0; q < 4; q++) {
    float g = iig[cb + q * 16 + lr], e = iib[cb + q * 16 + lr];
    ga2[q] = (f32x2){g, g}; be2[q] = (f32x2){e, e};
  }
#pragma unroll
  for (int q = 0; q < 4; q++)
#pragma unroll
    for (int rh = 0; rh < 2; rh++)
#pragma unroll
      for (int p = 0; p < 2; p++) {
        f32x2 a2 = (f32x2){acc[q][rh][2 * p], acc[q][rh][2 * p + 1]};
        f32x2 tt = pk_add(pk_add(a2, b42[q]), nmu[rh][p]);
        f32x2 p2 = pk_fma(pk_mul(tt, rv[rh][p]), ga2[q], be2[q]);
        float g10 = 1.f / (1.f + __expf(-p2[0]));
        float g11 = 1.f / (1.f + __expf(-p2[1]));
        unsigned w = gio[q][rh][p];
        gio[q][rh][p] = cvt_pk(g10 * bhalf(w, 0), g11 * bhalf(w, 1));
      }

  // ---- PH3: ug gate on gT; features = g2*param_out_ln + gio -> aT (pi) ----
  gemmQ(gT, ugWf, acc, wv, lane, lr, lh);
#pragma unroll
  for (int q = 0; q < 4; q++) { float b = ugb[cb + q * 16 + lr]; b42[q] = (f32x2){b, b}; }
  statsW(acc, b42, sP[1], qP[1], wv, lr, lh);
  __syncthreads();                              // S4
  statsR(sP[1], qP[1], nmu, rv, lh);
#pragma unroll
  for (int q = 0; q < 4; q++) {
    float g = nig[cb + q * 16 + lr], e = nib[cb + q * 16 + lr];
    ga2[q] = (f32x2){g, g}; be2[q] = (f32x2){e, e};
  }
#pragma unroll
  for (int rh = 0; rh < 2; rh++)
#pragma unroll
    for (int p = 0; p < 2; p++) {
      const int rrA = rh * 16 + lh * 4 + 2 * p;
      const float* po0 = param_out_ln + (size_t)div9(r0 + rrA) * 256;
      const float* po1 = param_out_ln + (size_t)div9(r0 + rrA + 1) * 256;
      float fA[4], fB[4];
#pragma unroll
      for (int q = 0; q < 4; q++) {
        f32x2 a2 = (f32x2){acc[q][rh][2 * p], acc[q][rh][2 * p + 1]};
        f32x2 tt = pk_add(pk_add(a2, b42[q]), nmu[rh][p]);
        f32x2 u2 = pk_fma(pk_mul(tt, rv[rh][p]), ga2[q], be2[q]);
        float g20 = 1.f / (1.f + __expf(-u2[0]));
        float g21 = 1.f / (1.f + __expf(-u2[1]));
        unsigned w = gio[q][rh][p];
        fA[q] = g20 * po0[cb + q * 16 + lr] + bhalf(w, 0);
        fB[q] = g21 * po1[cb + q * 16 + lr] + bhalf(w, 1);
      }
      uint2 pkA, pkB;
      pkA.x = cvt_pk(fA[0], fA[1]); pkA.y = cvt_pk(fA[2], fA[3]);
      pkB.x = cvt_pk(fB[0], fB[1]); pkB.y = cvt_pk(fB[2], fB[3]);
      *(uint2*)&aT[rrA * APITCH + cb + lr * 4] = pkA;
      *(uint2*)&aT[(rrA + 1) * APITCH + cb + lr * 4] = pkB;
    }
  __syncthreads();                              // S5: features published in aT

  // ---- PH4: fc (pi-permuted weights), LN, relu -> out ----
  gemmQ(aT, fcWf, acc, wv, lane, lr, lh);
#pragma unroll
  for (int q = 0; q < 4; q++) { float b = fcb[cb + q * 16 + lr]; b42[q] = (f32x2){b, b}; }
  statsW(acc, b42, sP[0], qP[0], wv, lr, lh);
  __syncthreads();                              // S6
  statsR(sP[0], qP[0], nmu, rv, lh);
#pragma unroll
  for (int q = 0; q < 4; q++) {
    float g = fng[cb + q * 16 + lr], e = fnb[cb + q * 16 + lr];
    ga2[q] = (f32x2){g, g}; be2[q] = (f32x2){e, e};
  }
#pragma unroll
  for (int q = 0; q < 4; q++) {
    const int col = cb + q * 16 + lr;
#pragma unroll
    for (int rh = 0; rh < 2; rh++)
#pragma unroll
      for (int p = 0; p < 2; p++) {
        f32x2 a2 = (f32x2){acc[q][rh][2 * p], acc[q][rh][2 * p + 1]};
        f32x2 tt = pk_add(pk_add(a2, b42[q]), nmu[rh][p]);
        f32x2 v2 = pk_fma(pk_mul(tt, rv[rh][p]), ga2[q], be2[q]);
        const int rrA = r0 + rh * 16 + lh * 4 + 2 * p;
        out[(size_t)rrA * 256 + col] = fmaxf(v2[0], 0.f);
        out[(size_t)(rrA + 1) * 256 + col] = fmaxf(v2[1], 0.f);
      }
  }
}

// ================= kernel 1: params (unchanged) =================
#define FPITCH 516

__device__ __forceinline__ void red8(float& s, float& q) {
#pragma unroll
  for (int m = 1; m < 8; m <<= 1) { s += __shfl_xor(s, m); q += __shfl_xor(q, m); }
}

__global__ __launch_bounds__(256) void k_params(
    const float* __restrict__ uf, const unsigned short* __restrict__ dynWf,
    const float* __restrict__ dynb, const float* __restrict__ nog,
    const float* __restrict__ nob, float* __restrict__ param_in,
    float* __restrict__ param_out_ln) {
  __shared__ short aT[32 * APITCH];
  __shared__ float fBuf[32 * FPITCH];
  const int t = threadIdx.x;
  const int wv = t >> 6, lane = t & 63, lr = lane & 15, lh = lane >> 4;
  const int r0 = blockIdx.x * 32;
#pragma unroll
  for (int j = 0; j < 8; j++) {
    const int idx4 = j * 256 + t;
    const int row = idx4 >> 6;
    const int c4 = (idx4 & 63) << 2;
    const float4 v = *(const float4*)&uf[(size_t)(r0 + row) * 256 + c4];
    uint2 pk;
    pk.x = cvt_pk(v.x, v.y);
    pk.y = cvt_pk(v.z, v.w);
    *(uint2*)&aT[row * APITCH + c4] = pk;
  }
  __syncthreads();
  bf16x8 a0[8], a1[8];
#pragma unroll
  for (int kk = 0; kk < 8; kk++) {
    a0[kk] = *(const bf16x8*)&aT[lr * APITCH + kk * 32 + lh * 8];
    a1[kk] = *(const bf16x8*)&aT[(16 + lr) * APITCH + kk * 32 + lh * 8];
  }
#pragma unroll 1
  for (int cp = 0; cp < 8; cp++) {
    const int ct = wv * 8 + cp;
    bf16x8 b[8];
#pragma unroll
    for (int kk = 0; kk < 8; kk++)
      b[kk] = *(const bf16x8*)&dynWf[((ct * 8 + kk) * 64 + lane) * 8];
    const float bi = dynb[ct * 16 + lr];
    f32x4 c0 = {0.f, 0.f, 0.f, 0.f}, c1 = c0;
#pragma unroll
    for (int kk = 0; kk < 8; kk++) {
      c0 = __builtin_amdgcn_mfma_f32_16x16x32_bf16(a0[kk], b[kk], c0, 0, 0, 0);
      c1 = __builtin_amdgcn_mfma_f32_16x16x32_bf16(a1[kk], b[kk], c1, 0, 0, 0);
    }
#pragma unroll
    for (int i = 0; i < 4; i++) {
      fBuf[(lh * 4 + i) * FPITCH + ct * 16 + lr] = c0[i] + bi;
      fBuf[(16 + lh * 4 + i) * FPITCH + ct * 16 + lr] = c1[i] + bi;
    }
  }
  __syncthreads();
  const int row = t >> 3, j = t & 7;
  float s = 0.f, q = 0.f;
#pragma unroll
  for (int i = 0; i < 32; i++) {
    float x = fBuf[row * FPITCH + 256 + j + 8 * i];
    s += x; q += x * x;
  }
  red8(s, q);
  const float mu = s * (1.f / 256.f);
  const float rsv = rsqrtf(q * (1.f / 256.f) - mu * mu + EPS);
#pragma unroll 1
  for (int i = 0; i < 32; i++) {
    const int c = j + 8 * i;
    float x = fBuf[row * FPITCH + 256 + c];
    param_out_ln[(size_t)(r0 + row) * 256 + c] = (x - mu) * rsv * nog[c] + nob[c];
  }
#pragma unroll
  for (int jj = 0; jj < 8; jj++) {
    const int idx4 = jj * 256 + t;
    const int rwq = idx4 >> 6;
    const int c4 = (idx4 & 63) << 2;
    float4 v;
    v.x = fBuf[rwq * FPITCH + c4 + 0];
    v.y = fBuf[rwq * FPITCH + c4 + 1];
    v.z = fBuf[rwq * FPITCH + c4 + 2];
    v.w = fBuf[rwq * FPITCH + c4 + 3];
    *(float4*)&param_in[(size_t)(r0 + rwq) * 256 + c4] = v;
  }
}

extern "C" void kernel_launch(void* const* d_in, const int* in_sizes, int n_in,
                              void* d_out, int out_size, void* d_ws, size_t ws_size,
                              hipStream_t stream) {
  const float* uf   = (const float*)d_in[0];
  const float* inf  = (const float*)d_in[1];
  const float* dynW = (const float*)d_in[2];
  const float* dynb = (const float*)d_in[3];
  const float* inpW = (const float*)d_in[4];
  const float* inpb = (const float*)d_in[5];
  const float* igW  = (const float*)d_in[6];
  const float* igb  = (const float*)d_in[7];
  const float* ugW  = (const float*)d_in[8];
  const float* ugb  = (const float*)d_in[9];
  const float* fcW  = (const float*)d_in[10];
  const float* fcb  = (const float*)d_in[11];
  const float* nig  = (const float*)d_in[12];
  const float* nib  = (const float*)d_in[13];
  const float* nog  = (const float*)d_in[14];
  const float* nob  = (const float*)d_in[15];
  const float* iig  = (const float*)d_in[16];
  const float* iib  = (const float*)d_in[17];
  const float* iog  = (const float*)d_in[18];
  const float* iob  = (const float*)d_in[19];
  const float* fng  = (const float*)d_in[20];
  const float* fnb  = (const float*)d_in[21];
  float* out = (float*)d_out;

  char* ws = (char*)d_ws;
  unsigned short* Wf = (unsigned short*)ws;
  unsigned short* dynWf = Wf;
  unsigned short* inpWf = Wf + 131072;
  unsigned short* igWf  = Wf + 262144;
  unsigned short* ugWf  = Wf + 327680;
  unsigned short* fcWf  = Wf + 393216;
  float* param_in     = (float*)(ws + (1 << 20));
  float* param_out_ln = (float*)(ws + (1 << 20) + (16 << 20));

  k_cvt_all<<<dim3(1792), dim3(256), 0, stream>>>(dynW, inpW, igW, ugW, fcW, Wf);

  k_params<<<dim3(512), dim3(256), 0, stream>>>(uf, dynWf, dynb, nog, nob,
                                                param_in, param_out_ln);

  k_main<<<dim3(4608), dim3(256), 0, stream>>>(
      inf, inpWf, inpb, igWf, igb, ugWf, ugb, fcWf, fcb,
      nig, nib, iig, iib, iog, iob, fng, fnb,
      param_in, param_out_ln, out);
}